// Round 7
// baseline (118.953 us; speedup 1.0000x reference)
//
#include <hip/hip_runtime.h>
#include <math.h>

#define BTOT 65536
#define NM   64
#define FIN  6
#define HID  64
#define FOUT 3

// d_out float32 layout (flat concat of reference tuple):
#define MO_OFF  0            // model_outputs (B,2,3) -> 393216
#define IDX_OFF 393216       // selection_indices (B) stored as float
#define LOG_OFF 458752       // selection_logits (B,64) = 1.0f
#define PRB_OFF 4653056      // selection_probabilities (B,64) = 1/64
#define OUT_END 8847360

typedef __attribute__((ext_vector_type(8))) short short8v;
typedef __attribute__((ext_vector_type(4))) float f32x4;

union AB { uint u[4]; uint4 q; short8v v; };

static __device__ __forceinline__ uint pack_hi2(float a, float b) {
    return (__float_as_uint(b) & 0xFFFF0000u) | (__float_as_uint(a) >> 16);
}
static __device__ __forceinline__ float hi_part(float a) {
    return __uint_as_float(__float_as_uint(a) & 0xFFFF0000u);
}
// split 8 f32 -> hi frag + lo frag (bf16 truncation; lo catches residual)
static __device__ __forceinline__ void split8(const float (&e)[8], AB& hi, AB& lo) {
#pragma unroll
    for (int t = 0; t < 4; ++t) {
        float a = e[2 * t], b = e[2 * t + 1];
        hi.u[t] = pack_hi2(a, b);
        lo.u[t] = pack_hi2(a - hi_part(a), b - hi_part(b));
    }
}
static __device__ __forceinline__ f32x4 mf(const AB& a, const AB& b, f32x4 c) {
    return __builtin_amdgcn_mfma_f32_16x16x32_bf16(a.v, b.v, c, 0, 0, 0);
}
// weight-row permutation: output feature o sits at (tile t, C-row i)
static __device__ __forceinline__ int permo(int t, int i) {
    return 32 * (i & 1) + 8 * (i >> 2) + 2 * t + ((i >> 1) & 1);
}

// ---------------- K1: selection index -> idx output + byte map ----------------
__global__ void k_index(const float* __restrict__ in, float* __restrict__ out,
                        unsigned char* __restrict__ wsb)
{
    const int b = blockIdx.x * 256 + threadIdx.x;
    const float xv = in[b * 6 + 0];
    const float zv = in[b * 6 + 2];
    const float TWO_PI = 6.28318530717958647692f;
    float af = (float)atan2((double)zv, (double)xv);
    float t = fmodf(af + TWO_PI, TWO_PI) / TWO_PI * 64.0f;
    int idx = (int)floorf(t);
    idx = min(max(idx, 0), 63);

    wsb[b] = (unsigned char)idx;
    out[IDX_OFF + b] = (float)idx;
}

// ---------------- K2: MFMA MLP, swapped operands (A=W, B=H^T) ----------------
// A-frag sets: 0..3 = L0 tiles (K=8: 6 inputs + bias-as-k6); 4..27 = L1..L3
// (set = 4 + ly*8 + ks*4 + t); 28..29 = LF (ks 0..1).
#define NSETS 30
#define LCAP  2048
#define L1S   4
#define L2S   12
#define L3S   20
#define LFS   28

__global__ __launch_bounds__(512, 4) void k_mlp(
    const float* __restrict__ in,
    const float* __restrict__ W0, const float* __restrict__ B0,
    const float* __restrict__ W1, const float* __restrict__ B1,
    const float* __restrict__ W2, const float* __restrict__ B2,
    const float* __restrict__ W3, const float* __restrict__ B3,
    const float* __restrict__ WF, const float* __restrict__ BF,
    const uint4* __restrict__ wsb4, float* __restrict__ out)
{
    __shared__ uint bhS[NSETS][64][4];          // 30720 B (hi plane, A-frags)
    __shared__ uint blS[NSETS][64][4];          // 30720 B (lo plane)
    __shared__ int list[LCAP];                  // 8192 B
    __shared__ int wtot[8];
    __shared__ int wbase[8];
    __shared__ int s_n;

    const int m = blockIdx.x;
    const int yy = (int)blockIdx.y;             // 0..7
    const int bid = yy * NM + m;                // 0..511
    const int tid = (int)threadIdx.x;
    const int wid = tid >> 6;
    const int lane = tid & 63;
    const int g = lane >> 4;
    const int c16 = lane & 15;

    // ---- staging: W rows (permuted) as A-fragment planes ----
    for (int job = tid; job < NSETS * 64; job += 512) {
        const int set = job >> 6, ln = job & 63;
        const int gq = ln >> 4, cq = ln & 15;
        float e[8];
        if (set < 4) {                                   // L0: K=6 +bias@k6
            const int o = permo(set, cq);
            if (gq == 0) {
                const float* w = W0 + m * (HID * FIN) + o * FIN;
#pragma unroll
                for (int j = 0; j < 8; ++j)
                    e[j] = (j < FIN) ? w[j] : ((j == 6) ? B0[m * HID + o] : 0.0f);
            } else {
#pragma unroll
                for (int j = 0; j < 8; ++j) e[j] = 0.0f;
            }
        } else if (set < 28) {                           // L1..L3
            const int q = set - 4;
            const int ly = q >> 3, ks = (q >> 2) & 1, t = q & 3;
            const int o = permo(t, cq);
            const float* Wl = (ly == 0) ? W1 : (ly == 1) ? W2 : W3;
            const float4* w4 = (const float4*)(Wl + m * (HID * HID) + o * HID + ks * 32 + gq * 8);
            float4 f0 = w4[0], f1 = w4[1];
            e[0] = f0.x; e[1] = f0.y; e[2] = f0.z; e[3] = f0.w;
            e[4] = f1.x; e[5] = f1.y; e[6] = f1.z; e[7] = f1.w;
        } else {                                         // LF (natural rows)
            const int ks = set - 28;
            if (cq < FOUT) {
                const float* w = WF + m * (FOUT * HID) + cq * HID + ks * 32 + gq * 8;
#pragma unroll
                for (int j = 0; j < 8; ++j) e[j] = w[j];
            } else {
#pragma unroll
                for (int j = 0; j < 8; ++j) e[j] = 0.0f;
            }
        }
        AB hi, lo;
        split8(e, hi, lo);
        *(uint4*)&bhS[set][ln][0] = hi.q;
        *(uint4*)&blS[set][ln][0] = lo.q;
    }

    // ---- constant fill (fire-and-forget stores drain under compute) ----
    {
        float4* __restrict__ out4 = (float4*)out;
        const int split = PRB_OFF / 4;
        const float4 ones = make_float4(1.0f, 1.0f, 1.0f, 1.0f);
        const float4 prob = make_float4(0.015625f, 0.015625f, 0.015625f, 0.015625f);
        const int i0 = LOG_OFF / 4 + bid * 4096 + tid;
#pragma unroll
        for (int k = 0; k < 8; ++k) {
            const int i = i0 + k * 512;
            out4[i] = (i < split) ? ones : prob;         // 512 blocks * 4096 = region
        }
    }

    // ---- gather: build this model's sample list from the byte map ----
    uint4 v[8];
    int c = 0;
#pragma unroll
    for (int j = 0; j < 8; ++j) {
        v[j] = wsb4[j * 512 + tid];
#pragma unroll
        for (int t = 0; t < 16; ++t) {
            const int bi = (int)((((const uint*)&v[j])[t >> 2] >> ((t & 3) * 8)) & 0xffu);
            c += (bi == m);
        }
    }
    int isc = c;
#pragma unroll
    for (int d = 1; d < 64; d <<= 1) {
        int y = __shfl_up(isc, d);
        if (lane >= d) isc += y;
    }
    if (lane == 63) wtot[wid] = isc;
    __syncthreads();
    if (tid == 0) {
        int run = 0;
#pragma unroll
        for (int w = 0; w < 8; ++w) { wbase[w] = run; run += wtot[w]; }
        s_n = run;
    }
    __syncthreads();
    int pos = wbase[wid] + (isc - c);
#pragma unroll
    for (int j = 0; j < 8; ++j) {
#pragma unroll
        for (int t = 0; t < 16; ++t) {
            const int bi = (int)((((const uint*)&v[j])[t >> 2] >> ((t & 3) * 8)) & 0xffu);
            if (bi == m) {
                if (pos < LCAP) list[pos] = (j * 512 + tid) * 16 + t;
                ++pos;
            }
        }
    }
    __syncthreads();
    const int n = min(s_n, LCAP);

    // hoist LF A-frags (loop-invariant)
    AB lfh[2], lfl[2];
#pragma unroll
    for (int ks = 0; ks < 2; ++ks) {
        lfh[ks].q = *(const uint4*)&bhS[LFS + ks][lane][0];
        lfl[ks].q = *(const uint4*)&blS[LFS + ks][lane][0];
    }
    const float bf0 = BF[m * FOUT + 0];
    const float bf1 = BF[m * FOUT + 1];
    const float bf2 = BF[m * FOUT + 2];

    const int nt = (n + 15) >> 4;                 // 16-sample tiles
    for (int ti = yy * 8 + wid; ti < nt; ti += 64) {
        const int s = ti * 16 + c16;
        const bool act = (s < n);
        const int b = list[act ? s : (n - 1)];

        // ---- L0: B = X^T (samples in columns), bias folded at k=6 ----
        AB xh, xl;
        if (g == 0) {
            const float* xp = in + b * 6;
            float e[8] = {xp[0], xp[1], xp[2], xp[3], xp[4], xp[5], 1.0f, 0.0f};
            split8(e, xh, xl);
        } else {
#pragma unroll
            for (int t = 0; t < 4; ++t) { xh.u[t] = 0u; xl.u[t] = 0u; }
        }
        f32x4 acc[4];
#pragma unroll
        for (int t = 0; t < 4; ++t) {
            AB ah, al;
            ah.q = *(const uint4*)&bhS[t][lane][0];
            al.q = *(const uint4*)&blS[t][lane][0];
            f32x4 cc = {0.0f, 0.0f, 0.0f, 0.0f};
            cc = mf(ah, xh, cc); cc = mf(ah, xl, cc); cc = mf(al, xh, cc);
            acc[t] = cc;
        }

        AB bh[2], bl[2];
        // H0 frag: relu(acc) (L0 bias already folded), feature f=ks*32+g*8+jj
        // lives at acc[jj>>1][2*(jj&1)+ks] in THIS lane (permutation magic).
#pragma unroll
        for (int ks = 0; ks < 2; ++ks) {
            float e[8];
#pragma unroll
            for (int jj = 0; jj < 8; ++jj)
                e[jj] = fmaxf(acc[jj >> 1][2 * (jj & 1) + ks], 0.0f);
            split8(e, bh[ks], bl[ks]);
        }

#define LAYERX(SET0)                                                          \
        _Pragma("unroll")                                                     \
        for (int ks = 0; ks < 2; ++ks)                                        \
        _Pragma("unroll")                                                     \
        for (int t = 0; t < 4; ++t) {                                         \
            AB ah, al;                                                        \
            ah.q = *(const uint4*)&bhS[(SET0) + ks * 4 + t][lane][0];          \
            al.q = *(const uint4*)&blS[(SET0) + ks * 4 + t][lane][0];          \
            f32x4 cc = (ks == 0) ? f32x4{0.0f, 0.0f, 0.0f, 0.0f} : acc[t];    \
            cc = mf(ah, bh[ks], cc);                                          \
            cc = mf(ah, bl[ks], cc);                                          \
            cc = mf(al, bh[ks], cc);                                          \
            acc[t] = cc;                                                      \
        }

#define BUILDF(BPTR)                                                          \
        _Pragma("unroll")                                                     \
        for (int ks = 0; ks < 2; ++ks) {                                      \
            const float4* bp = (const float4*)((BPTR) + ks * 32 + g * 8);     \
            float4 q0 = bp[0], q1 = bp[1];                                    \
            float bb[8] = {q0.x, q0.y, q0.z, q0.w, q1.x, q1.y, q1.z, q1.w};   \
            float e[8];                                                       \
            _Pragma("unroll")                                                 \
            for (int jj = 0; jj < 8; ++jj)                                    \
                e[jj] = fmaxf(acc[jj >> 1][2 * (jj & 1) + ks] + bb[jj], 0.0f);\
            split8(e, bh[ks], bl[ks]);                                        \
        }

#define LFINX(PASS)                                                           \
        {                                                                     \
            f32x4 o = {bf0, bf1, bf2, 0.0f};                                  \
            _Pragma("unroll")                                                 \
            for (int ks = 0; ks < 2; ++ks) {                                  \
                o = mf(lfh[ks], bh[ks], o);                                   \
                o = mf(lfh[ks], bl[ks], o);                                   \
                o = mf(lfl[ks], bh[ks], o);                                   \
            }                                                                 \
            if (g == 0 && act) {                                              \
                float* p = out + MO_OFF + b * 6 + (PASS) * 3;                 \
                p[0] = o[0]; p[1] = o[1]; p[2] = o[2];                        \
            }                                                                 \
        }

        LAYERX(L1S);           // acc = W1·H0
        BUILDF(B1 + m * HID);  // h1 frag (bias b1 + relu)
        LFINX(0);              // output after layer 1 (uses h1)
        LAYERX(L2S);           // acc = W2·H1
        BUILDF(B2 + m * HID);  // h2 frag
        LAYERX(L3S);           // acc = W3·H2
        BUILDF(B3 + m * HID);  // h3 frag
        LFINX(1);              // final output (uses h3)
    }
}

extern "C" void kernel_launch(void* const* d_in, const int* in_sizes, int n_in,
                              void* d_out, int out_size, void* d_ws, size_t ws_size,
                              hipStream_t stream)
{
    const float* in = (const float*)d_in[0];
    const float* W0 = (const float*)d_in[1];
    const float* B0 = (const float*)d_in[2];
    const float* W1 = (const float*)d_in[3];
    const float* B1 = (const float*)d_in[4];
    const float* W2 = (const float*)d_in[5];
    const float* B2 = (const float*)d_in[6];
    const float* W3 = (const float*)d_in[7];
    const float* B3 = (const float*)d_in[8];
    const float* WF = (const float*)d_in[9];
    const float* BF = (const float*)d_in[10];
    float* out = (float*)d_out;

    unsigned char* wsb = (unsigned char*)d_ws;    // 65536 bytes

    k_index<<<BTOT / 256, 256, 0, stream>>>(in, out, wsb);
    k_mlp<<<dim3(NM, 8), 512, 0, stream>>>(in, W0, B0, W1, B1, W2, B2, W3, B3,
                                           WF, BF, (const uint4*)wsb, out);
}

// Round 8
// 41.245 us; speedup vs baseline: 2.8841x; 2.8841x over previous
//
#include <hip/hip_runtime.h>
#include <math.h>

#define BTOT 65536
#define NM   64
#define FIN  6
#define HID  64
#define FOUT 3

// d_out float32 layout (flat concat of reference tuple):
#define MO_OFF  0            // model_outputs (B,2,3) -> 393216
#define IDX_OFF 393216       // selection_indices (B) stored as float
#define LOG_OFF 458752       // selection_logits (B,64) = 1.0f
#define PRB_OFF 4653056      // selection_probabilities (B,64) = 1/64
#define OUT_END 8847360

typedef __attribute__((ext_vector_type(8))) short short8v;
typedef __attribute__((ext_vector_type(4))) float f32x4;

union AB { uint u[4]; uint4 q; short8v v; };

static __device__ __forceinline__ uint pack_hi2(float a, float b) {
    return (__float_as_uint(b) & 0xFFFF0000u) | (__float_as_uint(a) >> 16);
}
static __device__ __forceinline__ float hi_part(float a) {
    return __uint_as_float(__float_as_uint(a) & 0xFFFF0000u);
}
// split 8 f32 -> hi frag + lo frag (bf16 truncation; lo catches residual)
static __device__ __forceinline__ void split8(const float (&e)[8], AB& hi, AB& lo) {
#pragma unroll
    for (int t = 0; t < 4; ++t) {
        float a = e[2 * t], b = e[2 * t + 1];
        hi.u[t] = pack_hi2(a, b);
        lo.u[t] = pack_hi2(a - hi_part(a), b - hi_part(b));
    }
}
static __device__ __forceinline__ f32x4 mf(const AB& a, const AB& b, f32x4 c) {
    return __builtin_amdgcn_mfma_f32_16x16x32_bf16(a.v, b.v, c, 0, 0, 0);
}

// ---------------- K1: selection index -> idx output + byte map ----------------
__global__ void k_index(const float* __restrict__ in, float* __restrict__ out,
                        unsigned char* __restrict__ wsb)
{
    const int b = blockIdx.x * 256 + threadIdx.x;
    const float xv = in[b * 6 + 0];
    const float zv = in[b * 6 + 2];
    const float TWO_PI = 6.28318530717958647692f;
    float af = (float)atan2((double)zv, (double)xv);
    float t = fmodf(af + TWO_PI, TWO_PI) / TWO_PI * 64.0f;
    int idx = (int)floorf(t);
    idx = min(max(idx, 0), 63);

    wsb[b] = (unsigned char)idx;
    out[IDX_OFF + b] = (float)idx;
}

// ---------------- K2: MFMA MLP (R4-verified math; 16 waves, 16-sample tiles) --
// B-frag sets: 0..3 = L0 (ntile 0..3); 4..27 = L1..L3 (8 each: ks*4+nt);
// 28..29 = LF (kstep 0..1).
#define NSETS 30
#define HSTRIDE 68
#define LCAP 2048
#define WAVES 16

__global__ __launch_bounds__(1024, 4) void k_mlp(
    const float* __restrict__ in,
    const float* __restrict__ W0, const float* __restrict__ B0,
    const float* __restrict__ W1, const float* __restrict__ B1,
    const float* __restrict__ W2, const float* __restrict__ B2,
    const float* __restrict__ W3, const float* __restrict__ B3,
    const float* __restrict__ WF, const float* __restrict__ BF,
    const uint4* __restrict__ wsb4, float* __restrict__ out)
{
    __shared__ uint bhS[NSETS][64][4];            // 30720 B (hi plane)
    __shared__ uint blS[NSETS][64][4];            // 30720 B (lo plane)
    __shared__ float hsS[WAVES][16 * HSTRIDE];    // 69632 B (per-wave H scratch)
    __shared__ int list[LCAP];                    // 8192 B
    __shared__ int wtot[WAVES];
    __shared__ int wbase[WAVES];
    __shared__ int s_n;

    const int m = blockIdx.x;
    const int yy = (int)blockIdx.y;               // 0..3
    const int bid = yy * NM + m;                  // 0..255
    const int tid = (int)threadIdx.x;
    const int wid = tid >> 6;                     // 0..15
    const int lane = tid & 63;
    const int g = lane >> 4;
    const int c16 = lane & 15;

    // ---- staging: convert+swizzle weights into B-fragment planes ----
    for (int job = tid; job < NSETS * 64; job += 1024) {
        const int set = job >> 6, ln = job & 63;
        const int gq = ln >> 4, cq = ln & 15;
        float e[8];
        if (set < 4) {                                   // L0: K=6 padded to 32
            const int col = set * 16 + cq;
            const float* w = W0 + m * (HID * FIN) + col * FIN;
            const int kb = gq * 8;
#pragma unroll
            for (int j = 0; j < 8; ++j) { int k = kb + j; e[j] = (k < FIN) ? w[k] : 0.0f; }
        } else if (set < 28) {                           // L1..L3
            const int q = set - 4;
            const int ly = q >> 3, ks = (q & 7) >> 2, nt = q & 3;
            const int col = nt * 16 + cq;
            const float* Wl = (ly == 0) ? W1 : (ly == 1) ? W2 : W3;
            const float4* w4 = (const float4*)(Wl + m * (HID * HID) + col * HID + ks * 32 + gq * 8);
            float4 f0 = w4[0], f1 = w4[1];
            e[0] = f0.x; e[1] = f0.y; e[2] = f0.z; e[3] = f0.w;
            e[4] = f1.x; e[5] = f1.y; e[6] = f1.z; e[7] = f1.w;
        } else {                                         // LF: 3 valid cols
            const int ks = set - 28;
            if (cq < FOUT) {
                const float* w = WF + m * (FOUT * HID) + cq * HID + ks * 32 + gq * 8;
#pragma unroll
                for (int j = 0; j < 8; ++j) e[j] = w[j];
            } else {
#pragma unroll
                for (int j = 0; j < 8; ++j) e[j] = 0.0f;
            }
        }
        AB hi, lo;
        split8(e, hi, lo);
        *(uint4*)&bhS[set][ln][0] = hi.q;
        *(uint4*)&blS[set][ln][0] = lo.q;
    }

    // ---- constant fill (stores drain under gather+compute) ----
    {
        float4* __restrict__ out4 = (float4*)out;
        const int split = PRB_OFF / 4;
        const float4 ones = make_float4(1.0f, 1.0f, 1.0f, 1.0f);
        const float4 prob = make_float4(0.015625f, 0.015625f, 0.015625f, 0.015625f);
        const int i0 = LOG_OFF / 4 + bid * 8192 + tid;
#pragma unroll
        for (int k = 0; k < 8; ++k) {
            const int i = i0 + k * 1024;
            out4[i] = (i < split) ? ones : prob;         // 256 blocks * 8192 = region
        }
    }

    // per-lane bias registers
    float b0v[4], b1v[4], b2v[4], b3v[4];
#pragma unroll
    for (int t = 0; t < 4; ++t) {
        const int c = t * 16 + c16;
        b0v[t] = B0[m * HID + c];
        b1v[t] = B1[m * HID + c];
        b2v[t] = B2[m * HID + c];
        b3v[t] = B3[m * HID + c];
    }
    const float bfv = (c16 < FOUT) ? BF[m * FOUT + c16] : 0.0f;

    // ---- gather: build this model's sample list from the byte map ----
    uint4 v[4];
    int c = 0;
#pragma unroll
    for (int j = 0; j < 4; ++j) {
        v[j] = wsb4[j * 1024 + tid];
#pragma unroll
        for (int t = 0; t < 16; ++t) {
            const int bi = (int)((((const uint*)&v[j])[t >> 2] >> ((t & 3) * 8)) & 0xffu);
            c += (bi == m);
        }
    }
    int isc = c;
#pragma unroll
    for (int d = 1; d < 64; d <<= 1) {
        int y = __shfl_up(isc, d);
        if (lane >= d) isc += y;
    }
    if (lane == 63) wtot[wid] = isc;
    __syncthreads();
    if (tid == 0) {
        int run = 0;
#pragma unroll
        for (int w = 0; w < WAVES; ++w) { wbase[w] = run; run += wtot[w]; }
        s_n = run;
    }
    __syncthreads();
    int pos = wbase[wid] + (isc - c);
#pragma unroll
    for (int j = 0; j < 4; ++j) {
#pragma unroll
        for (int t = 0; t < 16; ++t) {
            const int bi = (int)((((const uint*)&v[j])[t >> 2] >> ((t & 3) * 8)) & 0xffu);
            if (bi == m) {
                if (pos < LCAP) list[pos] = (j * 1024 + tid) * 16 + t;
                ++pos;
            }
        }
    }
    __syncthreads();
    const int n = min(s_n, LCAP);

    // hoist LF B-frags (loop-invariant, used twice per tile)
    AB lfh[2], lfl[2];
#pragma unroll
    for (int ks = 0; ks < 2; ++ks) {
        lfh[ks].q = *(const uint4*)&bhS[28 + ks][lane][0];
        lfl[ks].q = *(const uint4*)&blS[28 + ks][lane][0];
    }

    float* __restrict__ hw = hsS[wid];

    for (int ti = yy * WAVES + wid; ti * 16 < n; ti += 64) {
        f32x4 acc[4];
        AB ah[2], al[2];

        // ---- L0 ----
        AB a0h, a0l;
        if (g == 0) {
            int s = ti * 16 + c16; if (s >= n) s = n - 1;
            const int b = list[s];
            const float* xp = in + b * 6;
            float e[8];
#pragma unroll
            for (int j = 0; j < 8; ++j) e[j] = (j < FIN) ? xp[j] : 0.0f;
            split8(e, a0h, a0l);
        } else {
#pragma unroll
            for (int t = 0; t < 4; ++t) { a0h.u[t] = 0u; a0l.u[t] = 0u; }
        }
#pragma unroll
        for (int t = 0; t < 4; ++t) {
            AB bh, bl;
            bh.q = *(const uint4*)&bhS[t][lane][0];
            bl.q = *(const uint4*)&blS[t][lane][0];
            f32x4 cc = {b0v[t], b0v[t], b0v[t], b0v[t]};
            cc = mf(a0h, bh, cc); cc = mf(a0h, bl, cc); cc = mf(a0l, bh, cc);
            acc[t] = cc;
        }

#define STORE_RELU()                                                          \
        _Pragma("unroll")                                                     \
        for (int t = 0; t < 4; ++t)                                           \
        _Pragma("unroll")                                                     \
        for (int r = 0; r < 4; ++r) {                                         \
            float vv = fmaxf(acc[t][r], 0.0f);                                \
            const int row = g * 4 + r;                                        \
            const int col = (t * 16 + c16) ^ (r << 3);                        \
            hw[row * HSTRIDE + col] = vv;                                     \
        }

#define READ_A()                                                              \
        {                                                                     \
            const int row = c16;                                              \
            const int rb = row * HSTRIDE;                                     \
            const int rs = row & 3;                                           \
            _Pragma("unroll")                                                 \
            for (int ks = 0; ks < 2; ++ks) {                                  \
                const int cgs = (ks * 4 + g) ^ rs;                            \
                const float* p = hw + rb + cgs * 8;                           \
                float4 f0 = *(const float4*)p;                                \
                float4 f1 = *(const float4*)(p + 4);                          \
                float e[8] = {f0.x, f0.y, f0.z, f0.w, f1.x, f1.y, f1.z, f1.w};\
                split8(e, ah[ks], al[ks]);                                    \
            }                                                                 \
        }

#define LAYER64(SET0, BV)                                                     \
        _Pragma("unroll")                                                     \
        for (int ks = 0; ks < 2; ++ks)                                        \
        _Pragma("unroll")                                                     \
        for (int t = 0; t < 4; ++t) {                                         \
            AB bh, bl;                                                        \
            bh.q = *(const uint4*)&bhS[(SET0) + ks * 4 + t][lane][0];         \
            bl.q = *(const uint4*)&blS[(SET0) + ks * 4 + t][lane][0];         \
            f32x4 cc = (ks == 0) ? f32x4{BV[t], BV[t], BV[t], BV[t]}          \
                                 : acc[t];                                    \
            cc = mf(ah[ks], bh, cc);                                          \
            cc = mf(ah[ks], bl, cc);                                          \
            cc = mf(al[ks], bh, cc);                                          \
            acc[t] = cc;                                                      \
        }

#define LFINAL(PASS)                                                          \
        {                                                                     \
            f32x4 o = {bfv, bfv, bfv, bfv};                                   \
            _Pragma("unroll")                                                 \
            for (int ks = 0; ks < 2; ++ks) {                                  \
                o = mf(ah[ks], lfh[ks], o);                                   \
                o = mf(ah[ks], lfl[ks], o);                                   \
                o = mf(al[ks], lfh[ks], o);                                   \
            }                                                                 \
            _Pragma("unroll")                                                 \
            for (int r = 0; r < 4; ++r) {                                     \
                const int s = ti * 16 + g * 4 + r;                            \
                if (c16 < FOUT && s < n) {                                    \
                    const int b = list[s];                                    \
                    out[MO_OFF + b * 6 + (PASS) * 3 + c16] = o[r];            \
                }                                                             \
            }                                                                 \
        }

        STORE_RELU();     // H0
        READ_A();         // A = H0
        LAYER64(4, b1v);  // L1
        STORE_RELU();     // H1
        READ_A();         // A = H1
        LFINAL(0);        // output after layer 1
        LAYER64(12, b2v); // L2
        STORE_RELU();     // H2
        READ_A();         // A = H2
        LAYER64(20, b3v); // L3
        STORE_RELU();     // H3
        READ_A();         // A = H3
        LFINAL(1);        // final output
    }
}

extern "C" void kernel_launch(void* const* d_in, const int* in_sizes, int n_in,
                              void* d_out, int out_size, void* d_ws, size_t ws_size,
                              hipStream_t stream)
{
    const float* in = (const float*)d_in[0];
    const float* W0 = (const float*)d_in[1];
    const float* B0 = (const float*)d_in[2];
    const float* W1 = (const float*)d_in[3];
    const float* B1 = (const float*)d_in[4];
    const float* W2 = (const float*)d_in[5];
    const float* B2 = (const float*)d_in[6];
    const float* W3 = (const float*)d_in[7];
    const float* B3 = (const float*)d_in[8];
    const float* WF = (const float*)d_in[9];
    const float* BF = (const float*)d_in[10];
    float* out = (float*)d_out;

    unsigned char* wsb = (unsigned char*)d_ws;    // 65536 bytes

    k_index<<<BTOT / 256, 256, 0, stream>>>(in, out, wsb);
    k_mlp<<<dim3(NM, 4), 1024, 0, stream>>>(in, W0, B0, W1, B1, W2, B2, W3, B3,
                                            WF, BF, (const uint4*)wsb, out);
}